// Round 7
// baseline (4420.132 us; speedup 1.0000x reference)
//
#include <hip/hip_runtime.h>

#define D_MODEL 1024
#define NUM_HEADS 16
#define SEQ 2048
#define BATCH 2

__device__ __forceinline__ float bf2f(unsigned short u) {
    return __uint_as_float(((unsigned int)u) << 16);
}
__device__ __forceinline__ float bf2f_lo(unsigned int u) {
    return __uint_as_float(u << 16);
}
__device__ __forceinline__ float bf2f_hi(unsigned int u) {
    return __uint_as_float(u & 0xFFFF0000u);
}
__device__ __forceinline__ unsigned short f2bf(float f) {
    unsigned int u = __float_as_uint(f);
    return (unsigned short)((u + 0x7FFFu + ((u >> 16) & 1u)) >> 16);   // RTNE
}

// C[m,o] = sum_i A[m,i] * W[o,i]; A,W fp32. 64x64 tile, BK=16, 256 thr, 4x4/thread.
// which: 0=Q(rope), 1=K(rope), 2=V. Output layout [b][h][s][d] bf16 in ws.
__global__ __launch_bounds__(256) void qkv_gemm_kernel(
    const float* __restrict__ x,
    const float* __restrict__ Wq,
    const float* __restrict__ Wk,
    const float* __restrict__ Wv,
    unsigned short* __restrict__ qb, unsigned short* __restrict__ kb,
    unsigned short* __restrict__ vb)
{
    const int which = blockIdx.z;
    const float* __restrict__ W = (which == 0) ? Wq : ((which == 1) ? Wk : Wv);
    unsigned short* __restrict__ outp = (which == 0) ? qb : ((which == 1) ? kb : vb);
    const int m0 = blockIdx.y * 64;
    const int n0 = blockIdx.x * 64;

    __shared__ float As[64][17];
    __shared__ float Bs[64][17];

    const int tid = threadIdx.x;
    const int tx = tid & 15, ty = tid >> 4;
    const int ar = tid >> 2;            // 0..63
    const int ak = (tid & 3) * 4;       // 0,4,8,12

    float acc[4][4];
#pragma unroll
    for (int i = 0; i < 4; i++)
#pragma unroll
        for (int j = 0; j < 4; j++) acc[i][j] = 0.f;

    for (int kb_ = 0; kb_ < 1024; kb_ += 16) {
        float4 a4 = *reinterpret_cast<const float4*>(&x[(size_t)(m0 + ar) * 1024 + kb_ + ak]);
        float4 b4 = *reinterpret_cast<const float4*>(&W[(size_t)(n0 + ar) * 1024 + kb_ + ak]);
        As[ar][ak + 0] = a4.x; As[ar][ak + 1] = a4.y;
        As[ar][ak + 2] = a4.z; As[ar][ak + 3] = a4.w;
        Bs[ar][ak + 0] = b4.x; Bs[ar][ak + 1] = b4.y;
        Bs[ar][ak + 2] = b4.z; Bs[ar][ak + 3] = b4.w;
        __syncthreads();
#pragma unroll
        for (int kk = 0; kk < 16; kk++) {
            float a[4], b[4];
#pragma unroll
            for (int i = 0; i < 4; i++) a[i] = As[ty * 4 + i][kk];
#pragma unroll
            for (int j = 0; j < 4; j++) b[j] = Bs[tx * 4 + j][kk];
#pragma unroll
            for (int i = 0; i < 4; i++)
#pragma unroll
                for (int j = 0; j < 4; j++) acc[i][j] += a[i] * b[j];
        }
        __syncthreads();
    }

    const int h = n0 >> 6;   // whole 64-col tile is one head
    // d = tx*4+{0,1,2,3} -> pairs p0 = tx*2, p0+1; inv_freq[p] = 10000^(-p/32)
    const float invf0 = powf(10000.0f, -((float)(tx * 2)) / 32.0f);
    const float invf1 = powf(10000.0f, -((float)(tx * 2 + 1)) / 32.0f);
#pragma unroll
    for (int i = 0; i < 4; i++) {
        int m = m0 + ty * 4 + i;
        int s = m & (SEQ - 1);
        int bb = m >> 11;
        size_t base = (((size_t)bb * NUM_HEADS + h) * SEQ + s) * 64 + tx * 4;
        ushort4 o4;
        if (which < 2) {
            float c0, s0, c1, s1;
            sincosf((float)s * invf0, &s0, &c0);
            sincosf((float)s * invf1, &s1, &c1);
            o4.x = f2bf(acc[i][0] * c0 - acc[i][1] * s0);
            o4.y = f2bf(acc[i][0] * s0 + acc[i][1] * c0);
            o4.z = f2bf(acc[i][2] * c1 - acc[i][3] * s1);
            o4.w = f2bf(acc[i][2] * s1 + acc[i][3] * c1);
        } else {
            o4.x = f2bf(acc[i][0]); o4.y = f2bf(acc[i][1]);
            o4.z = f2bf(acc[i][2]); o4.w = f2bf(acc[i][3]);
        }
        *reinterpret_cast<ushort4*>(&outp[base]) = o4;
    }
}

// Scalar flash attention: one thread per query row. Block = 256 rows x one (b,h).
// Branch-free online softmax in registers; K/V tiles staged in LDS.
__global__ __launch_bounds__(256) void attn_kernel(
    const unsigned short* __restrict__ qb, const unsigned short* __restrict__ kb,
    const unsigned short* __restrict__ vb, unsigned short* __restrict__ ab)
{
    const int bi = blockIdx.x;    // 0..7
    const int bh = blockIdx.y;    // 0..31
    const int b = bh >> 4, h = bh & 15;
    const size_t base = (size_t)bh * SEQ * 64;
    const int tid = threadIdx.x;
    const int i = bi * 256 + tid;   // my query row (0..2047)

    __shared__ float Ks[64][65];
    __shared__ float Vs[64][65];

    float q[64];
    {
        const unsigned short* qp = qb + base + (size_t)i * 64;
#pragma unroll
        for (int u = 0; u < 8; u++) {
            uint4 qv = *reinterpret_cast<const uint4*>(qp + u * 8);
            q[u * 8 + 0] = bf2f_lo(qv.x); q[u * 8 + 1] = bf2f_hi(qv.x);
            q[u * 8 + 2] = bf2f_lo(qv.y); q[u * 8 + 3] = bf2f_hi(qv.y);
            q[u * 8 + 4] = bf2f_lo(qv.z); q[u * 8 + 5] = bf2f_hi(qv.z);
            q[u * 8 + 6] = bf2f_lo(qv.w); q[u * 8 + 7] = bf2f_hi(qv.w);
        }
    }

    float m_i = -1e30f, l_i = 0.f;
    float O[64];
#pragma unroll
    for (int c = 0; c < 64; c++) O[c] = 0.f;

    const int ntiles = bi * 4 + 4;   // keys up to row bi*256+255
    for (int kt = 0; kt < ntiles; kt++) {
        const int j0 = kt * 64;
        __syncthreads();   // prior-iter Ks/Vs reads done
#pragma unroll
        for (int u = 0; u < 2; u++) {
            int fi = tid + u * 256;
            int row = fi >> 3;
            int e8 = (fi & 7) * 8;
            uint4 kv = *reinterpret_cast<const uint4*>(&kb[base + (size_t)(j0 + row) * 64 + e8]);
            Ks[row][e8 + 0] = bf2f_lo(kv.x); Ks[row][e8 + 1] = bf2f_hi(kv.x);
            Ks[row][e8 + 2] = bf2f_lo(kv.y); Ks[row][e8 + 3] = bf2f_hi(kv.y);
            Ks[row][e8 + 4] = bf2f_lo(kv.z); Ks[row][e8 + 5] = bf2f_hi(kv.z);
            Ks[row][e8 + 6] = bf2f_lo(kv.w); Ks[row][e8 + 7] = bf2f_hi(kv.w);
            uint4 vv = *reinterpret_cast<const uint4*>(&vb[base + (size_t)(j0 + row) * 64 + e8]);
            Vs[row][e8 + 0] = bf2f_lo(vv.x); Vs[row][e8 + 1] = bf2f_hi(vv.x);
            Vs[row][e8 + 2] = bf2f_lo(vv.y); Vs[row][e8 + 3] = bf2f_hi(vv.y);
            Vs[row][e8 + 4] = bf2f_lo(vv.z); Vs[row][e8 + 5] = bf2f_hi(vv.z);
            Vs[row][e8 + 6] = bf2f_lo(vv.w); Vs[row][e8 + 7] = bf2f_hi(vv.w);
        }
        __syncthreads();

        int nk = i - j0 + 1;         // valid keys in this tile for my row
        if (nk > 64) nk = 64;
        for (int jj = 0; jj < nk; jj++) {
            float s = 0.f;
#pragma unroll
            for (int kk = 0; kk < 64; kk++) s += q[kk] * Ks[jj][kk];
            s *= 0.125f;
            float mn = fmaxf(m_i, s);
            float alpha = __expf(m_i - mn);   // 0 on first key
            float pv    = __expf(s - mn);
            l_i = l_i * alpha + pv;
#pragma unroll
            for (int c = 0; c < 64; c++) O[c] = O[c] * alpha + pv * Vs[jj][c];
            m_i = mn;
        }
    }

    float inv = 1.0f / l_i;
    unsigned short* op = ab + ((size_t)b * SEQ + i) * 1024 + h * 64;
#pragma unroll
    for (int u = 0; u < 8; u++) {
        uint4 ov;
        ov.x = (unsigned int)f2bf(O[u * 8 + 0] * inv) | (((unsigned int)f2bf(O[u * 8 + 1] * inv)) << 16);
        ov.y = (unsigned int)f2bf(O[u * 8 + 2] * inv) | (((unsigned int)f2bf(O[u * 8 + 3] * inv)) << 16);
        ov.z = (unsigned int)f2bf(O[u * 8 + 4] * inv) | (((unsigned int)f2bf(O[u * 8 + 5] * inv)) << 16);
        ov.w = (unsigned int)f2bf(O[u * 8 + 6] * inv) | (((unsigned int)f2bf(O[u * 8 + 7] * inv)) << 16);
        *reinterpret_cast<uint4*>(op + u * 8) = ov;
    }
}

// out[m,o] = sum_i A[m,i] * Wo[o,i]; A bf16 (ws), Wo fp32, OUT FP32.
__global__ __launch_bounds__(256) void out_gemm_kernel(
    const unsigned short* __restrict__ A, const float* __restrict__ Wo,
    float* __restrict__ out)
{
    const int m0 = blockIdx.y * 64;
    const int n0 = blockIdx.x * 64;

    __shared__ float As[64][17];
    __shared__ float Bs[64][17];

    const int tid = threadIdx.x;
    const int tx = tid & 15, ty = tid >> 4;
    const int ar = tid >> 2;
    const int ak = (tid & 3) * 4;

    float acc[4][4];
#pragma unroll
    for (int i = 0; i < 4; i++)
#pragma unroll
        for (int j = 0; j < 4; j++) acc[i][j] = 0.f;

    for (int kb_ = 0; kb_ < 1024; kb_ += 16) {
        ushort4 a4 = *reinterpret_cast<const ushort4*>(&A[(size_t)(m0 + ar) * 1024 + kb_ + ak]);
        float4 b4 = *reinterpret_cast<const float4*>(&Wo[(size_t)(n0 + ar) * 1024 + kb_ + ak]);
        As[ar][ak + 0] = bf2f(a4.x); As[ar][ak + 1] = bf2f(a4.y);
        As[ar][ak + 2] = bf2f(a4.z); As[ar][ak + 3] = bf2f(a4.w);
        Bs[ar][ak + 0] = b4.x; Bs[ar][ak + 1] = b4.y;
        Bs[ar][ak + 2] = b4.z; Bs[ar][ak + 3] = b4.w;
        __syncthreads();
#pragma unroll
        for (int kk = 0; kk < 16; kk++) {
            float a[4], b[4];
#pragma unroll
            for (int i = 0; i < 4; i++) a[i] = As[ty * 4 + i][kk];
#pragma unroll
            for (int j = 0; j < 4; j++) b[j] = Bs[tx * 4 + j][kk];
#pragma unroll
            for (int i = 0; i < 4; i++)
#pragma unroll
                for (int j = 0; j < 4; j++) acc[i][j] += a[i] * b[j];
        }
        __syncthreads();
    }

#pragma unroll
    for (int i = 0; i < 4; i++) {
        int m = m0 + ty * 4 + i;
        float4 o4 = make_float4(acc[i][0], acc[i][1], acc[i][2], acc[i][3]);
        *reinterpret_cast<float4*>(&out[(size_t)m * 1024 + n0 + tx * 4]) = o4;
    }
}

extern "C" void kernel_launch(void* const* d_in, const int* in_sizes, int n_in,
                              void* d_out, int out_size, void* d_ws, size_t ws_size,
                              hipStream_t stream)
{
    const float* x  = (const float*)d_in[0];
    const float* Wq = (const float*)d_in[1];
    const float* Wk = (const float*)d_in[2];
    const float* Wv = (const float*)d_in[3];
    const float* Wo = (const float*)d_in[4];
    float* out = (float*)d_out;   // reference output dtype is float32

    const size_t QKV_ELEMS = (size_t)BATCH * SEQ * D_MODEL;  // 4194304

    // ws: exactly 4 x 8 MB bf16 buffers = 32 MB
    unsigned short* qb = (unsigned short*)d_ws;
    unsigned short* kb = qb + QKV_ELEMS;
    unsigned short* vb = kb + QKV_ELEMS;
    unsigned short* ab = vb + QKV_ELEMS;

    qkv_gemm_kernel<<<dim3(16, 64, 3), 256, 0, stream>>>(x, Wq, Wk, Wv, qb, kb, vb);
    attn_kernel<<<dim3(8, 32), 256, 0, stream>>>(qb, kb, vb, ab);
    out_gemm_kernel<<<dim3(16, 64), 256, 0, stream>>>(ab, Wo, out);
}

// Round 8
// 2545.595 us; speedup vs baseline: 1.7364x; 1.7364x over previous
//
#include <hip/hip_runtime.h>

#define D_MODEL 1024
#define NUM_HEADS 16
#define SEQ 2048
#define BATCH 2

__device__ __forceinline__ float bf2f(unsigned short u) {
    return __uint_as_float(((unsigned int)u) << 16);
}
__device__ __forceinline__ float bf2f_lo(unsigned int u) {
    return __uint_as_float(u << 16);
}
__device__ __forceinline__ float bf2f_hi(unsigned int u) {
    return __uint_as_float(u & 0xFFFF0000u);
}
__device__ __forceinline__ unsigned short f2bf(float f) {
    unsigned int u = __float_as_uint(f);
    return (unsigned short)((u + 0x7FFFu + ((u >> 16) & 1u)) >> 16);   // RTNE
}

// C[m,o] = sum_i A[m,i] * W[o,i]; A,W fp32. 64x64 tile, BK=16, 256 thr, 4x4/thread.
// which: 0=Q(rope), 1=K(rope), 2=V. Output layout [b][h][s][d] bf16 in ws.
__global__ __launch_bounds__(256) void qkv_gemm_kernel(
    const float* __restrict__ x,
    const float* __restrict__ Wq,
    const float* __restrict__ Wk,
    const float* __restrict__ Wv,
    unsigned short* __restrict__ qb, unsigned short* __restrict__ kb,
    unsigned short* __restrict__ vb)
{
    const int which = blockIdx.z;
    const float* __restrict__ W = (which == 0) ? Wq : ((which == 1) ? Wk : Wv);
    unsigned short* __restrict__ outp = (which == 0) ? qb : ((which == 1) ? kb : vb);
    const int m0 = blockIdx.y * 64;
    const int n0 = blockIdx.x * 64;

    __shared__ float As[64][17];
    __shared__ float Bs[64][17];

    const int tid = threadIdx.x;
    const int tx = tid & 15, ty = tid >> 4;
    const int ar = tid >> 2;            // 0..63
    const int ak = (tid & 3) * 4;       // 0,4,8,12

    float acc[4][4];
#pragma unroll
    for (int i = 0; i < 4; i++)
#pragma unroll
        for (int j = 0; j < 4; j++) acc[i][j] = 0.f;

    for (int kb_ = 0; kb_ < 1024; kb_ += 16) {
        float4 a4 = *reinterpret_cast<const float4*>(&x[(size_t)(m0 + ar) * 1024 + kb_ + ak]);
        float4 b4 = *reinterpret_cast<const float4*>(&W[(size_t)(n0 + ar) * 1024 + kb_ + ak]);
        As[ar][ak + 0] = a4.x; As[ar][ak + 1] = a4.y;
        As[ar][ak + 2] = a4.z; As[ar][ak + 3] = a4.w;
        Bs[ar][ak + 0] = b4.x; Bs[ar][ak + 1] = b4.y;
        Bs[ar][ak + 2] = b4.z; Bs[ar][ak + 3] = b4.w;
        __syncthreads();
#pragma unroll
        for (int kk = 0; kk < 16; kk++) {
            float a[4], b[4];
#pragma unroll
            for (int i = 0; i < 4; i++) a[i] = As[ty * 4 + i][kk];
#pragma unroll
            for (int j = 0; j < 4; j++) b[j] = Bs[tx * 4 + j][kk];
#pragma unroll
            for (int i = 0; i < 4; i++)
#pragma unroll
                for (int j = 0; j < 4; j++) acc[i][j] += a[i] * b[j];
        }
        __syncthreads();
    }

    const int h = n0 >> 6;   // whole 64-col tile is one head
    const float invf0 = powf(10000.0f, -((float)(tx * 2)) / 32.0f);
    const float invf1 = powf(10000.0f, -((float)(tx * 2 + 1)) / 32.0f);
#pragma unroll
    for (int i = 0; i < 4; i++) {
        int m = m0 + ty * 4 + i;
        int s = m & (SEQ - 1);
        int bb = m >> 11;
        size_t base = (((size_t)bb * NUM_HEADS + h) * SEQ + s) * 64 + tx * 4;
        ushort4 o4;
        if (which < 2) {
            float c0, s0, c1, s1;
            sincosf((float)s * invf0, &s0, &c0);
            sincosf((float)s * invf1, &s1, &c1);
            o4.x = f2bf(acc[i][0] * c0 - acc[i][1] * s0);
            o4.y = f2bf(acc[i][0] * s0 + acc[i][1] * c0);
            o4.z = f2bf(acc[i][2] * c1 - acc[i][3] * s1);
            o4.w = f2bf(acc[i][2] * s1 + acc[i][3] * c1);
        } else {
            o4.x = f2bf(acc[i][0]); o4.y = f2bf(acc[i][1]);
            o4.z = f2bf(acc[i][2]); o4.w = f2bf(acc[i][3]);
        }
        *reinterpret_cast<ushort4*>(&outp[base]) = o4;
    }
}

// Tiled flash attention: block = (64-row q-tile) x (b,h). 256 threads:
// thread t owns row r=t/4, col-group g=t%4 (16 score cols / 16 O cols).
// Cross-validated: bit-identical to the scalar reference kernel (R3==R4).
__global__ __launch_bounds__(256) void attn_kernel(
    const unsigned short* __restrict__ qb, const unsigned short* __restrict__ kb,
    const unsigned short* __restrict__ vb, unsigned short* __restrict__ ab)
{
    const int it = blockIdx.x;    // 0..31
    const int bh = blockIdx.y;    // 0..31
    const int b = bh >> 4, h = bh & 15;
    const size_t base = (size_t)bh * SEQ * 64;
    const unsigned short* __restrict__ Q = qb + base;
    const unsigned short* __restrict__ K = kb + base;
    const unsigned short* __restrict__ V = vb + base;

    __shared__ float Qs[64][65];
    __shared__ float KPs[64][65];   // K tile; reused as P tile
    __shared__ float Vs[64][65];

    const int tid = threadIdx.x;
    const int r = tid >> 2;   // 0..63
    const int g = tid & 3;    // 0..3
    const int i0 = it * 64;

    // Q tile: 64x64 bf16 = 512 uint4
#pragma unroll
    for (int u = 0; u < 2; u++) {
        int fi = tid + u * 256;          // 0..511
        int row = fi >> 3;
        int e8 = (fi & 7) * 8;
        uint4 qv = *reinterpret_cast<const uint4*>(&Q[(size_t)(i0 + row) * 64 + e8]);
        Qs[row][e8 + 0] = bf2f_lo(qv.x); Qs[row][e8 + 1] = bf2f_hi(qv.x);
        Qs[row][e8 + 2] = bf2f_lo(qv.y); Qs[row][e8 + 3] = bf2f_hi(qv.y);
        Qs[row][e8 + 4] = bf2f_lo(qv.z); Qs[row][e8 + 5] = bf2f_hi(qv.z);
        Qs[row][e8 + 6] = bf2f_lo(qv.w); Qs[row][e8 + 7] = bf2f_hi(qv.w);
    }

    float m_i = -1e30f, l_i = 0.f;
    float O[16];
#pragma unroll
    for (int c = 0; c < 16; c++) O[c] = 0.f;

    for (int jt = 0; jt <= it; jt++) {
        const int j0 = jt * 64;
        __syncthreads();   // Qs ready (1st iter); prior-iter KPs/Vs reads done
#pragma unroll
        for (int u = 0; u < 2; u++) {
            int fi = tid + u * 256;
            int row = fi >> 3;
            int e8 = (fi & 7) * 8;
            uint4 kv = *reinterpret_cast<const uint4*>(&K[(size_t)(j0 + row) * 64 + e8]);
            KPs[row][e8 + 0] = bf2f_lo(kv.x); KPs[row][e8 + 1] = bf2f_hi(kv.x);
            KPs[row][e8 + 2] = bf2f_lo(kv.y); KPs[row][e8 + 3] = bf2f_hi(kv.y);
            KPs[row][e8 + 4] = bf2f_lo(kv.z); KPs[row][e8 + 5] = bf2f_hi(kv.z);
            KPs[row][e8 + 6] = bf2f_lo(kv.w); KPs[row][e8 + 7] = bf2f_hi(kv.w);
            uint4 vv = *reinterpret_cast<const uint4*>(&V[(size_t)(j0 + row) * 64 + e8]);
            Vs[row][e8 + 0] = bf2f_lo(vv.x); Vs[row][e8 + 1] = bf2f_hi(vv.x);
            Vs[row][e8 + 2] = bf2f_lo(vv.y); Vs[row][e8 + 3] = bf2f_hi(vv.y);
            Vs[row][e8 + 4] = bf2f_lo(vv.z); Vs[row][e8 + 5] = bf2f_hi(vv.z);
            Vs[row][e8 + 6] = bf2f_lo(vv.w); Vs[row][e8 + 7] = bf2f_hi(vv.w);
        }
        __syncthreads();

        float sc[16];
#pragma unroll
        for (int jj = 0; jj < 16; jj++) sc[jj] = 0.f;
        for (int kk = 0; kk < 64; kk++) {
            float q = Qs[r][kk];
#pragma unroll
            for (int jj = 0; jj < 16; jj++) sc[jj] += q * KPs[g * 16 + jj][kk];
        }

        const int gi = i0 + r;
        float tm = -1e30f;
#pragma unroll
        for (int jj = 0; jj < 16; jj++) {
            int gj = j0 + g * 16 + jj;
            sc[jj] = (gj <= gi) ? sc[jj] * 0.125f : -1e30f;
            tm = fmaxf(tm, sc[jj]);
        }
        tm = fmaxf(tm, __shfl_xor(tm, 1));
        tm = fmaxf(tm, __shfl_xor(tm, 2));
        float m_new = fmaxf(m_i, tm);            // finite always (diag has >=1 valid)
        float alpha = __expf(m_i - m_new);
        float p[16];
        float tl = 0.f;
#pragma unroll
        for (int jj = 0; jj < 16; jj++) { p[jj] = __expf(sc[jj] - m_new); tl += p[jj]; }
        tl += __shfl_xor(tl, 1);
        tl += __shfl_xor(tl, 2);
        l_i = l_i * alpha + tl;
        m_i = m_new;
#pragma unroll
        for (int c = 0; c < 16; c++) O[c] *= alpha;

        __syncthreads();   // all K reads done -> safe to overwrite as P
#pragma unroll
        for (int jj = 0; jj < 16; jj++) KPs[r][g * 16 + jj] = p[jj];
        __syncthreads();

        for (int kk = 0; kk < 64; kk++) {
            float pp = KPs[r][kk];
#pragma unroll
            for (int c = 0; c < 16; c++) O[c] += pp * Vs[kk][g * 16 + c];
        }
    }

    float inv = 1.0f / l_i;
    const int gi = i0 + r;
    size_t ob = ((size_t)b * SEQ + gi) * 1024 + h * 64 + g * 16;
#pragma unroll
    for (int u = 0; u < 4; u++) {
        ushort4 o4;
        o4.x = f2bf(O[u * 4 + 0] * inv);
        o4.y = f2bf(O[u * 4 + 1] * inv);
        o4.z = f2bf(O[u * 4 + 2] * inv);
        o4.w = f2bf(O[u * 4 + 3] * inv);
        *reinterpret_cast<ushort4*>(&ab[ob + u * 4]) = o4;
    }
}

// out[m,o] = sum_i A[m,i] * Wo[o,i]; A bf16 (ws), Wo fp32, OUT FP32.
__global__ __launch_bounds__(256) void out_gemm_kernel(
    const unsigned short* __restrict__ A, const float* __restrict__ Wo,
    float* __restrict__ out)
{
    const int m0 = blockIdx.y * 64;
    const int n0 = blockIdx.x * 64;

    __shared__ float As[64][17];
    __shared__ float Bs[64][17];

    const int tid = threadIdx.x;
    const int tx = tid & 15, ty = tid >> 4;
    const int ar = tid >> 2;
    const int ak = (tid & 3) * 4;

    float acc[4][4];
#pragma unroll
    for (int i = 0; i < 4; i++)
#pragma unroll
        for (int j = 0; j < 4; j++) acc[i][j] = 0.f;

    for (int kb_ = 0; kb_ < 1024; kb_ += 16) {
        ushort4 a4 = *reinterpret_cast<const ushort4*>(&A[(size_t)(m0 + ar) * 1024 + kb_ + ak]);
        float4 b4 = *reinterpret_cast<const float4*>(&Wo[(size_t)(n0 + ar) * 1024 + kb_ + ak]);
        As[ar][ak + 0] = bf2f(a4.x); As[ar][ak + 1] = bf2f(a4.y);
        As[ar][ak + 2] = bf2f(a4.z); As[ar][ak + 3] = bf2f(a4.w);
        Bs[ar][ak + 0] = b4.x; Bs[ar][ak + 1] = b4.y;
        Bs[ar][ak + 2] = b4.z; Bs[ar][ak + 3] = b4.w;
        __syncthreads();
#pragma unroll
        for (int kk = 0; kk < 16; kk++) {
            float a[4], b[4];
#pragma unroll
            for (int i = 0; i < 4; i++) a[i] = As[ty * 4 + i][kk];
#pragma unroll
            for (int j = 0; j < 4; j++) b[j] = Bs[tx * 4 + j][kk];
#pragma unroll
            for (int i = 0; i < 4; i++)
#pragma unroll
                for (int j = 0; j < 4; j++) acc[i][j] += a[i] * b[j];
        }
        __syncthreads();
    }

#pragma unroll
    for (int i = 0; i < 4; i++) {
        int m = m0 + ty * 4 + i;
        float4 o4 = make_float4(acc[i][0], acc[i][1], acc[i][2], acc[i][3]);
        *reinterpret_cast<float4*>(&out[(size_t)m * 1024 + n0 + tx * 4]) = o4;
    }
}

extern "C" void kernel_launch(void* const* d_in, const int* in_sizes, int n_in,
                              void* d_out, int out_size, void* d_ws, size_t ws_size,
                              hipStream_t stream)
{
    const float* x  = (const float*)d_in[0];
    const float* Wq = (const float*)d_in[1];
    const float* Wk = (const float*)d_in[2];
    const float* Wv = (const float*)d_in[3];
    const float* Wo = (const float*)d_in[4];
    float* out = (float*)d_out;   // fp32 output

    const size_t QKV_ELEMS = (size_t)BATCH * SEQ * D_MODEL;  // 4194304

    // ws: exactly 4 x 8 MB bf16 buffers = 32 MB
    unsigned short* qb = (unsigned short*)d_ws;
    unsigned short* kb = qb + QKV_ELEMS;
    unsigned short* vb = kb + QKV_ELEMS;
    unsigned short* ab = vb + QKV_ELEMS;

    qkv_gemm_kernel<<<dim3(16, 64, 3), 256, 0, stream>>>(x, Wq, Wk, Wv, qb, kb, vb);
    attn_kernel<<<dim3(32, 32), 256, 0, stream>>>(qb, kb, vb, ab);
    out_gemm_kernel<<<dim3(16, 64), 256, 0, stream>>>(ab, Wo, out);
}

// Round 9
// 968.316 us; speedup vs baseline: 4.5648x; 2.6289x over previous
//
#include <hip/hip_runtime.h>

#define D_MODEL 1024
#define NUM_HEADS 16
#define SEQ 2048
#define BATCH 2

typedef __attribute__((ext_vector_type(8))) short bf16x8;
typedef __attribute__((ext_vector_type(4))) float f32x4;

__device__ __forceinline__ float bf2f(unsigned short u) {
    return __uint_as_float(((unsigned int)u) << 16);
}
__device__ __forceinline__ unsigned short f2bf(float f) {
    unsigned int u = __float_as_uint(f);
    return (unsigned short)((u + 0x7FFFu + ((u >> 16) & 1u)) >> 16);   // RTNE
}

// C[m,o] = sum_i A[m,i] * W[o,i]; A,W fp32. 64x64 tile, BK=16, 256 thr, 4x4/thread.
// which: 0=Q(rope), 1=K(rope), 2=V. Output layout [b][h][s][d] bf16 in ws.
__global__ __launch_bounds__(256) void qkv_gemm_kernel(
    const float* __restrict__ x,
    const float* __restrict__ Wq,
    const float* __restrict__ Wk,
    const float* __restrict__ Wv,
    unsigned short* __restrict__ qb, unsigned short* __restrict__ kb,
    unsigned short* __restrict__ vb)
{
    const int which = blockIdx.z;
    const float* __restrict__ W = (which == 0) ? Wq : ((which == 1) ? Wk : Wv);
    unsigned short* __restrict__ outp = (which == 0) ? qb : ((which == 1) ? kb : vb);
    const int m0 = blockIdx.y * 64;
    const int n0 = blockIdx.x * 64;

    __shared__ float As[64][17];
    __shared__ float Bs[64][17];

    const int tid = threadIdx.x;
    const int tx = tid & 15, ty = tid >> 4;
    const int ar = tid >> 2;            // 0..63
    const int ak = (tid & 3) * 4;       // 0,4,8,12

    float acc[4][4];
#pragma unroll
    for (int i = 0; i < 4; i++)
#pragma unroll
        for (int j = 0; j < 4; j++) acc[i][j] = 0.f;

    for (int kb_ = 0; kb_ < 1024; kb_ += 16) {
        float4 a4 = *reinterpret_cast<const float4*>(&x[(size_t)(m0 + ar) * 1024 + kb_ + ak]);
        float4 b4 = *reinterpret_cast<const float4*>(&W[(size_t)(n0 + ar) * 1024 + kb_ + ak]);
        As[ar][ak + 0] = a4.x; As[ar][ak + 1] = a4.y;
        As[ar][ak + 2] = a4.z; As[ar][ak + 3] = a4.w;
        Bs[ar][ak + 0] = b4.x; Bs[ar][ak + 1] = b4.y;
        Bs[ar][ak + 2] = b4.z; Bs[ar][ak + 3] = b4.w;
        __syncthreads();
#pragma unroll
        for (int kk = 0; kk < 16; kk++) {
            float a[4], b[4];
#pragma unroll
            for (int i = 0; i < 4; i++) a[i] = As[ty * 4 + i][kk];
#pragma unroll
            for (int j = 0; j < 4; j++) b[j] = Bs[tx * 4 + j][kk];
#pragma unroll
            for (int i = 0; i < 4; i++)
#pragma unroll
                for (int j = 0; j < 4; j++) acc[i][j] += a[i] * b[j];
        }
        __syncthreads();
    }

    const int h = n0 >> 6;   // whole 64-col tile is one head
    const float invf0 = powf(10000.0f, -((float)(tx * 2)) / 32.0f);
    const float invf1 = powf(10000.0f, -((float)(tx * 2 + 1)) / 32.0f);
#pragma unroll
    for (int i = 0; i < 4; i++) {
        int m = m0 + ty * 4 + i;
        int s = m & (SEQ - 1);
        int bb = m >> 11;
        size_t base = (((size_t)bb * NUM_HEADS + h) * SEQ + s) * 64 + tx * 4;
        ushort4 o4;
        if (which < 2) {
            float c0, s0, c1, s1;
            sincosf((float)s * invf0, &s0, &c0);
            sincosf((float)s * invf1, &s1, &c1);
            o4.x = f2bf(acc[i][0] * c0 - acc[i][1] * s0);
            o4.y = f2bf(acc[i][0] * s0 + acc[i][1] * c0);
            o4.z = f2bf(acc[i][2] * c1 - acc[i][3] * s1);
            o4.w = f2bf(acc[i][2] * s1 + acc[i][3] * c1);
        } else {
            o4.x = f2bf(acc[i][0]); o4.y = f2bf(acc[i][1]);
            o4.z = f2bf(acc[i][2]); o4.w = f2bf(acc[i][3]);
        }
        *reinterpret_cast<ushort4*>(&outp[base]) = o4;
    }
}

// MFMA flash attention. Block = 64-row Q-tile x (b,h); 4 waves, each owns a
// 16-row band. mfma_f32_16x16x32_bf16:
//   A[m=lane&15][k=quad*8+j], B[k=quad*8+j][n=lane&15], D[row=quad*4+reg][col=lane&15]
__global__ __launch_bounds__(256) void attn_kernel(
    const unsigned short* __restrict__ qb, const unsigned short* __restrict__ kb,
    const unsigned short* __restrict__ vb, unsigned short* __restrict__ ab)
{
    const int it = blockIdx.x;    // 0..31
    const int bh = blockIdx.y;    // 0..31
    const int b = bh >> 4, h = bh & 15;
    const size_t base = (size_t)bh * SEQ * 64;
    const int tid = threadIdx.x;
    const int w = tid >> 6;       // wave 0..3
    const int lane = tid & 63;
    const int quad = lane >> 4;   // 0..3
    const int c15 = lane & 15;
    const int i0 = it * 64;

    __shared__ __align__(16) unsigned short Vt[64][72];  // V^T tile [d][j], shared
    __shared__ __align__(16) unsigned short Pl[64][72];  // P bands, wave-private rows

    // Q fragments (A operand), k-steps s=0,1 — loaded once, kept in registers
    const int qrow = i0 + w * 16 + c15;
    bf16x8 qf0 = *reinterpret_cast<const bf16x8*>(&qb[base + (size_t)qrow * 64 + quad * 8]);
    bf16x8 qf1 = *reinterpret_cast<const bf16x8*>(&qb[base + (size_t)qrow * 64 + 32 + quad * 8]);

    float m_st[4], l_st[4];
    f32x4 Oc[4];
#pragma unroll
    for (int r = 0; r < 4; r++) { m_st[r] = -1e30f; l_st[r] = 0.f; }
#pragma unroll
    for (int t = 0; t < 4; t++) Oc[t] = (f32x4){0.f, 0.f, 0.f, 0.f};

    for (int jt = 0; jt <= it; jt++) {
        const int j0 = jt * 64;

        __syncthreads();   // prior-iter Vt reads done
        {   // stage V^T: thread handles V row (tid&63), 8-col chunks
            int row = tid & 63;
            int c8 = (tid >> 6) * 8;
#pragma unroll
            for (int u = 0; u < 2; u++) {
                int cc = c8 + u * 32;
                uint4 vv = *reinterpret_cast<const uint4*>(&vb[base + (size_t)(j0 + row) * 64 + cc]);
                const unsigned short* pv = reinterpret_cast<const unsigned short*>(&vv);
#pragma unroll
                for (int e = 0; e < 8; e++) Vt[cc + e][row] = pv[e];
            }
        }
        __syncthreads();

        // S band = Q K^T (16x64): K fragments straight from global
        f32x4 sc[4];
#pragma unroll
        for (int t = 0; t < 4; t++) sc[t] = (f32x4){0.f, 0.f, 0.f, 0.f};
#pragma unroll
        for (int t = 0; t < 4; t++) {
            const unsigned short* kr = &kb[base + (size_t)(j0 + t * 16 + c15) * 64];
            bf16x8 k0 = *reinterpret_cast<const bf16x8*>(kr + quad * 8);
            bf16x8 k1 = *reinterpret_cast<const bf16x8*>(kr + 32 + quad * 8);
            sc[t] = __builtin_amdgcn_mfma_f32_16x16x32_bf16(qf0, k0, sc[t], 0, 0, 0);
            sc[t] = __builtin_amdgcn_mfma_f32_16x16x32_bf16(qf1, k1, sc[t], 0, 0, 0);
        }

#pragma unroll
        for (int t = 0; t < 4; t++)
#pragma unroll
            for (int r = 0; r < 4; r++) sc[t][r] *= 0.125f;
        if (jt == it) {   // causal mask only on the diagonal tile
#pragma unroll
            for (int t = 0; t < 4; t++) {
                int gj = j0 + t * 16 + c15;
#pragma unroll
                for (int r = 0; r < 4; r++) {
                    int gi = i0 + w * 16 + quad * 4 + r;
                    if (gj > gi) sc[t][r] = -1e30f;
                }
            }
        }

        // online softmax (state per row = per (quad,reg), replicated over 16 col-lanes)
        float mnew[4], alpha[4], rsum[4];
#pragma unroll
        for (int r = 0; r < 4; r++) {
            float tm = fmaxf(fmaxf(sc[0][r], sc[1][r]), fmaxf(sc[2][r], sc[3][r]));
            tm = fmaxf(tm, __shfl_xor(tm, 1));
            tm = fmaxf(tm, __shfl_xor(tm, 2));
            tm = fmaxf(tm, __shfl_xor(tm, 4));
            tm = fmaxf(tm, __shfl_xor(tm, 8));
            mnew[r] = fmaxf(m_st[r], tm);
            alpha[r] = __expf(m_st[r] - mnew[r]);
            rsum[r] = 0.f;
        }
#pragma unroll
        for (int t = 0; t < 4; t++) {
#pragma unroll
            for (int r = 0; r < 4; r++) {
                float p = __expf(sc[t][r] - mnew[r]);
                rsum[r] += p;
                Pl[w * 16 + quad * 4 + r][t * 16 + c15] = f2bf(p);
            }
        }
#pragma unroll
        for (int r = 0; r < 4; r++) {
            float s = rsum[r];
            s += __shfl_xor(s, 1);
            s += __shfl_xor(s, 2);
            s += __shfl_xor(s, 4);
            s += __shfl_xor(s, 8);
            l_st[r] = l_st[r] * alpha[r] + s;
            m_st[r] = mnew[r];
#pragma unroll
            for (int t = 0; t < 4; t++) Oc[t][r] *= alpha[r];
        }

        // O += P V : A = P band (wave-private LDS rows), B = V^T tile
        bf16x8 ap0 = *reinterpret_cast<const bf16x8*>(&Pl[w * 16 + c15][quad * 8]);
        bf16x8 ap1 = *reinterpret_cast<const bf16x8*>(&Pl[w * 16 + c15][32 + quad * 8]);
#pragma unroll
        for (int t = 0; t < 4; t++) {
            bf16x8 bv0 = *reinterpret_cast<const bf16x8*>(&Vt[t * 16 + c15][quad * 8]);
            bf16x8 bv1 = *reinterpret_cast<const bf16x8*>(&Vt[t * 16 + c15][32 + quad * 8]);
            Oc[t] = __builtin_amdgcn_mfma_f32_16x16x32_bf16(ap0, bv0, Oc[t], 0, 0, 0);
            Oc[t] = __builtin_amdgcn_mfma_f32_16x16x32_bf16(ap1, bv1, Oc[t], 0, 0, 0);
        }
    }

#pragma unroll
    for (int r = 0; r < 4; r++) {
        float inv = 1.0f / l_st[r];
        int gi = i0 + w * 16 + quad * 4 + r;
        size_t ob = ((size_t)b * SEQ + gi) * 1024 + h * 64;
#pragma unroll
        for (int t = 0; t < 4; t++)
            ab[ob + t * 16 + c15] = f2bf(Oc[t][r] * inv);
    }
}

// out[m,o] = sum_i A[m,i] * Wo[o,i]; A bf16 (ws), Wo fp32, OUT FP32.
__global__ __launch_bounds__(256) void out_gemm_kernel(
    const unsigned short* __restrict__ A, const float* __restrict__ Wo,
    float* __restrict__ out)
{
    const int m0 = blockIdx.y * 64;
    const int n0 = blockIdx.x * 64;

    __shared__ float As[64][17];
    __shared__ float Bs[64][17];

    const int tid = threadIdx.x;
    const int tx = tid & 15, ty = tid >> 4;
    const int ar = tid >> 2;
    const int ak = (tid & 3) * 4;

    float acc[4][4];
#pragma unroll
    for (int i = 0; i < 4; i++)
#pragma unroll
        for (int j = 0; j < 4; j++) acc[i][j] = 0.f;

    for (int kb_ = 0; kb_ < 1024; kb_ += 16) {
        ushort4 a4 = *reinterpret_cast<const ushort4*>(&A[(size_t)(m0 + ar) * 1024 + kb_ + ak]);
        float4 b4 = *reinterpret_cast<const float4*>(&Wo[(size_t)(n0 + ar) * 1024 + kb_ + ak]);
        As[ar][ak + 0] = bf2f(a4.x); As[ar][ak + 1] = bf2f(a4.y);
        As[ar][ak + 2] = bf2f(a4.z); As[ar][ak + 3] = bf2f(a4.w);
        Bs[ar][ak + 0] = b4.x; Bs[ar][ak + 1] = b4.y;
        Bs[ar][ak + 2] = b4.z; Bs[ar][ak + 3] = b4.w;
        __syncthreads();
#pragma unroll
        for (int kk = 0; kk < 16; kk++) {
            float a[4], b[4];
#pragma unroll
            for (int i = 0; i < 4; i++) a[i] = As[ty * 4 + i][kk];
#pragma unroll
            for (int j = 0; j < 4; j++) b[j] = Bs[tx * 4 + j][kk];
#pragma unroll
            for (int i = 0; i < 4; i++)
#pragma unroll
                for (int j = 0; j < 4; j++) acc[i][j] += a[i] * b[j];
        }
        __syncthreads();
    }

#pragma unroll
    for (int i = 0; i < 4; i++) {
        int m = m0 + ty * 4 + i;
        float4 o4 = make_float4(acc[i][0], acc[i][1], acc[i][2], acc[i][3]);
        *reinterpret_cast<float4*>(&out[(size_t)m * 1024 + n0 + tx * 4]) = o4;
    }
}

extern "C" void kernel_launch(void* const* d_in, const int* in_sizes, int n_in,
                              void* d_out, int out_size, void* d_ws, size_t ws_size,
                              hipStream_t stream)
{
    const float* x  = (const float*)d_in[0];
    const float* Wq = (const float*)d_in[1];
    const float* Wk = (const float*)d_in[2];
    const float* Wv = (const float*)d_in[3];
    const float* Wo = (const float*)d_in[4];
    float* out = (float*)d_out;   // fp32 output

    const size_t QKV_ELEMS = (size_t)BATCH * SEQ * D_MODEL;  // 4194304

    // ws: exactly 4 x 8 MB bf16 buffers = 32 MB
    unsigned short* qb = (unsigned short*)d_ws;
    unsigned short* kb = qb + QKV_ELEMS;
    unsigned short* vb = kb + QKV_ELEMS;
    unsigned short* ab = vb + QKV_ELEMS;

    qkv_gemm_kernel<<<dim3(16, 64, 3), 256, 0, stream>>>(x, Wq, Wk, Wv, qb, kb, vb);
    attn_kernel<<<dim3(32, 32), 256, 0, stream>>>(qb, kb, vb, ab);
    out_gemm_kernel<<<dim3(16, 64), 256, 0, stream>>>(ab, Wo, out);
}

// Round 10
// 854.204 us; speedup vs baseline: 5.1746x; 1.1336x over previous
//
#include <hip/hip_runtime.h>

#define D_MODEL 1024
#define NUM_HEADS 16
#define SEQ 2048
#define BATCH 2

typedef __attribute__((ext_vector_type(8))) short bf16x8;
typedef __attribute__((ext_vector_type(4))) float f32x4;

__device__ __forceinline__ float bf2f(unsigned short u) {
    return __uint_as_float(((unsigned int)u) << 16);
}
__device__ __forceinline__ unsigned short f2bf(float f) {
    unsigned int u = __float_as_uint(f);
    return (unsigned short)((u + 0x7FFFu + ((u >> 16) & 1u)) >> 16);   // RTNE
}
__device__ __forceinline__ ushort4 pack4(float4 v) {
    return make_ushort4(f2bf(v.x), f2bf(v.y), f2bf(v.z), f2bf(v.w));
}

// MFMA NT-GEMM: C[m,n] = sum_i A[m,i] * W[n,i], fp32 inputs staged to bf16 LDS.
// 128x128 tile, BK=32, 256 thr = 4 waves, wave quadrant 64x64 (4x4 MFMAs).
// which: 0=Q(rope), 1=K(rope), 2=V. Output [b][h][s][d] bf16 in ws.
__global__ __launch_bounds__(256) void qkv_mfma_kernel(
    const float* __restrict__ x,
    const float* __restrict__ Wq,
    const float* __restrict__ Wk,
    const float* __restrict__ Wv,
    unsigned short* __restrict__ qb, unsigned short* __restrict__ kb,
    unsigned short* __restrict__ vb)
{
    const int which = blockIdx.z;
    const float* __restrict__ W = (which == 0) ? Wq : ((which == 1) ? Wk : Wv);
    unsigned short* __restrict__ outp = (which == 0) ? qb : ((which == 1) ? kb : vb);
    const int m0 = blockIdx.y * 128;
    const int n0g = blockIdx.x * 128;

    __shared__ __align__(16) unsigned short As[128][40];  // 80 B stride: 16B-aligned b128
    __shared__ __align__(16) unsigned short Bs[128][40];

    const int tid = threadIdx.x;
    const int w = tid >> 6;         // wave 0..3
    const int lane = tid & 63;
    const int quad = lane >> 4;     // 0..3
    const int c15 = lane & 15;
    const int qm = w >> 1, qn = w & 1;   // 64x64 quadrant

    const int srow = tid >> 1;          // 0..127
    const int scol = (tid & 1) * 16;    // 0 / 16

    f32x4 acc[4][4];
#pragma unroll
    for (int mi = 0; mi < 4; mi++)
#pragma unroll
        for (int ni = 0; ni < 4; ni++) acc[mi][ni] = (f32x4){0.f, 0.f, 0.f, 0.f};

    for (int kb0 = 0; kb0 < 1024; kb0 += 32) {
        const float* ap = x + (size_t)(m0 + srow) * 1024 + kb0 + scol;
        float4 a0 = *reinterpret_cast<const float4*>(ap + 0);
        float4 a1 = *reinterpret_cast<const float4*>(ap + 4);
        float4 a2 = *reinterpret_cast<const float4*>(ap + 8);
        float4 a3 = *reinterpret_cast<const float4*>(ap + 12);
        const float* wp = W + (size_t)(n0g + srow) * 1024 + kb0 + scol;
        float4 b0 = *reinterpret_cast<const float4*>(wp + 0);
        float4 b1 = *reinterpret_cast<const float4*>(wp + 4);
        float4 b2 = *reinterpret_cast<const float4*>(wp + 8);
        float4 b3 = *reinterpret_cast<const float4*>(wp + 12);

        __syncthreads();   // prior-iter fragment reads done
        {
            ushort4* ad = reinterpret_cast<ushort4*>(&As[srow][scol]);
            ad[0] = pack4(a0); ad[1] = pack4(a1); ad[2] = pack4(a2); ad[3] = pack4(a3);
            ushort4* bd = reinterpret_cast<ushort4*>(&Bs[srow][scol]);
            bd[0] = pack4(b0); bd[1] = pack4(b1); bd[2] = pack4(b2); bd[3] = pack4(b3);
        }
        __syncthreads();

        bf16x8 af[4], bfr[4];
#pragma unroll
        for (int mi = 0; mi < 4; mi++)
            af[mi] = *reinterpret_cast<const bf16x8*>(&As[qm * 64 + mi * 16 + c15][quad * 8]);
#pragma unroll
        for (int ni = 0; ni < 4; ni++)
            bfr[ni] = *reinterpret_cast<const bf16x8*>(&Bs[qn * 64 + ni * 16 + c15][quad * 8]);
#pragma unroll
        for (int mi = 0; mi < 4; mi++)
#pragma unroll
            for (int ni = 0; ni < 4; ni++)
                acc[mi][ni] = __builtin_amdgcn_mfma_f32_16x16x32_bf16(af[mi], bfr[ni], acc[mi][ni], 0, 0, 0);
    }

    // Epilogue. n = n0g + qn*64 + ni*16 + c15 -> h = n>>6 (quadrant-uniform), d = ni*16+c15.
    const int hq = (n0g + qn * 64) >> 6;
    if (which < 2) {
        float invf[4];
#pragma unroll
        for (int ni = 0; ni < 4; ni++)
            invf[ni] = powf(10000.0f, -((float)((ni * 16 + c15) >> 1)) / 32.0f);
        const int odd = c15 & 1;
#pragma unroll
        for (int mi = 0; mi < 4; mi++) {
#pragma unroll
            for (int r = 0; r < 4; r++) {
                int m = m0 + qm * 64 + mi * 16 + quad * 4 + r;
                int s = m & (SEQ - 1);
                int bb = m >> 11;
                size_t rowb = (((size_t)bb * NUM_HEADS + hq) * SEQ + s) * 64;
#pragma unroll
                for (int ni = 0; ni < 4; ni++) {
                    float val = acc[mi][ni][r];
                    float part = __shfl_xor(val, 1);
                    float sn, cs;
                    sincosf((float)s * invf[ni], &sn, &cs);
                    float nv = odd ? (part * sn + val * cs) : (val * cs - part * sn);
                    outp[rowb + ni * 16 + c15] = f2bf(nv);
                }
            }
        }
    } else {
#pragma unroll
        for (int mi = 0; mi < 4; mi++) {
#pragma unroll
            for (int r = 0; r < 4; r++) {
                int m = m0 + qm * 64 + mi * 16 + quad * 4 + r;
                int s = m & (SEQ - 1);
                int bb = m >> 11;
                size_t rowb = (((size_t)bb * NUM_HEADS + hq) * SEQ + s) * 64;
#pragma unroll
                for (int ni = 0; ni < 4; ni++)
                    outp[rowb + ni * 16 + c15] = f2bf(acc[mi][ni][r]);
            }
        }
    }
}

// MFMA flash attention (unchanged from R9 — validated).
__global__ __launch_bounds__(256) void attn_kernel(
    const unsigned short* __restrict__ qb, const unsigned short* __restrict__ kb,
    const unsigned short* __restrict__ vb, unsigned short* __restrict__ ab)
{
    const int it = blockIdx.x;    // 0..31
    const int bh = blockIdx.y;    // 0..31
    const int b = bh >> 4, h = bh & 15;
    const size_t base = (size_t)bh * SEQ * 64;
    const int tid = threadIdx.x;
    const int w = tid >> 6;
    const int lane = tid & 63;
    const int quad = lane >> 4;
    const int c15 = lane & 15;
    const int i0 = it * 64;

    __shared__ __align__(16) unsigned short Vt[64][72];
    __shared__ __align__(16) unsigned short Pl[64][72];

    const int qrow = i0 + w * 16 + c15;
    bf16x8 qf0 = *reinterpret_cast<const bf16x8*>(&qb[base + (size_t)qrow * 64 + quad * 8]);
    bf16x8 qf1 = *reinterpret_cast<const bf16x8*>(&qb[base + (size_t)qrow * 64 + 32 + quad * 8]);

    float m_st[4], l_st[4];
    f32x4 Oc[4];
#pragma unroll
    for (int r = 0; r < 4; r++) { m_st[r] = -1e30f; l_st[r] = 0.f; }
#pragma unroll
    for (int t = 0; t < 4; t++) Oc[t] = (f32x4){0.f, 0.f, 0.f, 0.f};

    for (int jt = 0; jt <= it; jt++) {
        const int j0 = jt * 64;

        __syncthreads();
        {
            int row = tid & 63;
            int c8 = (tid >> 6) * 8;
#pragma unroll
            for (int u = 0; u < 2; u++) {
                int cc = c8 + u * 32;
                uint4 vv = *reinterpret_cast<const uint4*>(&vb[base + (size_t)(j0 + row) * 64 + cc]);
                const unsigned short* pv = reinterpret_cast<const unsigned short*>(&vv);
#pragma unroll
                for (int e = 0; e < 8; e++) Vt[cc + e][row] = pv[e];
            }
        }
        __syncthreads();

        f32x4 sc[4];
#pragma unroll
        for (int t = 0; t < 4; t++) sc[t] = (f32x4){0.f, 0.f, 0.f, 0.f};
#pragma unroll
        for (int t = 0; t < 4; t++) {
            const unsigned short* kr = &kb[base + (size_t)(j0 + t * 16 + c15) * 64];
            bf16x8 k0 = *reinterpret_cast<const bf16x8*>(kr + quad * 8);
            bf16x8 k1 = *reinterpret_cast<const bf16x8*>(kr + 32 + quad * 8);
            sc[t] = __builtin_amdgcn_mfma_f32_16x16x32_bf16(qf0, k0, sc[t], 0, 0, 0);
            sc[t] = __builtin_amdgcn_mfma_f32_16x16x32_bf16(qf1, k1, sc[t], 0, 0, 0);
        }

#pragma unroll
        for (int t = 0; t < 4; t++)
#pragma unroll
            for (int r = 0; r < 4; r++) sc[t][r] *= 0.125f;
        if (jt == it) {
#pragma unroll
            for (int t = 0; t < 4; t++) {
                int gj = j0 + t * 16 + c15;
#pragma unroll
                for (int r = 0; r < 4; r++) {
                    int gi = i0 + w * 16 + quad * 4 + r;
                    if (gj > gi) sc[t][r] = -1e30f;
                }
            }
        }

        float mnew[4], alpha[4], rsum[4];
#pragma unroll
        for (int r = 0; r < 4; r++) {
            float tm = fmaxf(fmaxf(sc[0][r], sc[1][r]), fmaxf(sc[2][r], sc[3][r]));
            tm = fmaxf(tm, __shfl_xor(tm, 1));
            tm = fmaxf(tm, __shfl_xor(tm, 2));
            tm = fmaxf(tm, __shfl_xor(tm, 4));
            tm = fmaxf(tm, __shfl_xor(tm, 8));
            mnew[r] = fmaxf(m_st[r], tm);
            alpha[r] = __expf(m_st[r] - mnew[r]);
            rsum[r] = 0.f;
        }
#pragma unroll
        for (int t = 0; t < 4; t++) {
#pragma unroll
            for (int r = 0; r < 4; r++) {
                float p = __expf(sc[t][r] - mnew[r]);
                rsum[r] += p;
                Pl[w * 16 + quad * 4 + r][t * 16 + c15] = f2bf(p);
            }
        }
#pragma unroll
        for (int r = 0; r < 4; r++) {
            float s = rsum[r];
            s += __shfl_xor(s, 1);
            s += __shfl_xor(s, 2);
            s += __shfl_xor(s, 4);
            s += __shfl_xor(s, 8);
            l_st[r] = l_st[r] * alpha[r] + s;
            m_st[r] = mnew[r];
#pragma unroll
            for (int t = 0; t < 4; t++) Oc[t][r] *= alpha[r];
        }

        bf16x8 ap0 = *reinterpret_cast<const bf16x8*>(&Pl[w * 16 + c15][quad * 8]);
        bf16x8 ap1 = *reinterpret_cast<const bf16x8*>(&Pl[w * 16 + c15][32 + quad * 8]);
#pragma unroll
        for (int t = 0; t < 4; t++) {
            bf16x8 bv0 = *reinterpret_cast<const bf16x8*>(&Vt[t * 16 + c15][quad * 8]);
            bf16x8 bv1 = *reinterpret_cast<const bf16x8*>(&Vt[t * 16 + c15][32 + quad * 8]);
            Oc[t] = __builtin_amdgcn_mfma_f32_16x16x32_bf16(ap0, bv0, Oc[t], 0, 0, 0);
            Oc[t] = __builtin_amdgcn_mfma_f32_16x16x32_bf16(ap1, bv1, Oc[t], 0, 0, 0);
        }
    }

#pragma unroll
    for (int r = 0; r < 4; r++) {
        float inv = 1.0f / l_st[r];
        int gi = i0 + w * 16 + quad * 4 + r;
        size_t ob = ((size_t)b * SEQ + gi) * 1024 + h * 64;
#pragma unroll
        for (int t = 0; t < 4; t++)
            ab[ob + t * 16 + c15] = f2bf(Oc[t][r] * inv);
    }
}

// MFMA NT-GEMM: out[m,o] = sum_i ab[m,i] * Wo[o,i]; ab bf16 (ws), Wo fp32, out fp32.
__global__ __launch_bounds__(256) void out_mfma_kernel(
    const unsigned short* __restrict__ A, const float* __restrict__ Wo,
    float* __restrict__ out)
{
    const int m0 = blockIdx.y * 128;
    const int n0g = blockIdx.x * 128;

    __shared__ __align__(16) unsigned short As[128][40];
    __shared__ __align__(16) unsigned short Bs[128][40];

    const int tid = threadIdx.x;
    const int w = tid >> 6;
    const int lane = tid & 63;
    const int quad = lane >> 4;
    const int c15 = lane & 15;
    const int qm = w >> 1, qn = w & 1;

    const int srow = tid >> 1;
    const int scol = (tid & 1) * 16;

    f32x4 acc[4][4];
#pragma unroll
    for (int mi = 0; mi < 4; mi++)
#pragma unroll
        for (int ni = 0; ni < 4; ni++) acc[mi][ni] = (f32x4){0.f, 0.f, 0.f, 0.f};

    for (int kb0 = 0; kb0 < 1024; kb0 += 32) {
        const unsigned short* ap = A + (size_t)(m0 + srow) * 1024 + kb0 + scol;
        uint4 av0 = *reinterpret_cast<const uint4*>(ap);
        uint4 av1 = *reinterpret_cast<const uint4*>(ap + 8);
        const float* wp = Wo + (size_t)(n0g + srow) * 1024 + kb0 + scol;
        float4 b0 = *reinterpret_cast<const float4*>(wp + 0);
        float4 b1 = *reinterpret_cast<const float4*>(wp + 4);
        float4 b2 = *reinterpret_cast<const float4*>(wp + 8);
        float4 b3 = *reinterpret_cast<const float4*>(wp + 12);

        __syncthreads();
        {
            uint4* ad = reinterpret_cast<uint4*>(&As[srow][scol]);
            ad[0] = av0; ad[1] = av1;
            ushort4* bd = reinterpret_cast<ushort4*>(&Bs[srow][scol]);
            bd[0] = pack4(b0); bd[1] = pack4(b1); bd[2] = pack4(b2); bd[3] = pack4(b3);
        }
        __syncthreads();

        bf16x8 af[4], bfr[4];
#pragma unroll
        for (int mi = 0; mi < 4; mi++)
            af[mi] = *reinterpret_cast<const bf16x8*>(&As[qm * 64 + mi * 16 + c15][quad * 8]);
#pragma unroll
        for (int ni = 0; ni < 4; ni++)
            bfr[ni] = *reinterpret_cast<const bf16x8*>(&Bs[qn * 64 + ni * 16 + c15][quad * 8]);
#pragma unroll
        for (int mi = 0; mi < 4; mi++)
#pragma unroll
            for (int ni = 0; ni < 4; ni++)
                acc[mi][ni] = __builtin_amdgcn_mfma_f32_16x16x32_bf16(af[mi], bfr[ni], acc[mi][ni], 0, 0, 0);
    }

#pragma unroll
    for (int mi = 0; mi < 4; mi++) {
#pragma unroll
        for (int r = 0; r < 4; r++) {
            int m = m0 + qm * 64 + mi * 16 + quad * 4 + r;
#pragma unroll
            for (int ni = 0; ni < 4; ni++) {
                int n = n0g + qn * 64 + ni * 16 + c15;
                out[(size_t)m * 1024 + n] = acc[mi][ni][r];
            }
        }
    }
}

extern "C" void kernel_launch(void* const* d_in, const int* in_sizes, int n_in,
                              void* d_out, int out_size, void* d_ws, size_t ws_size,
                              hipStream_t stream)
{
    const float* x  = (const float*)d_in[0];
    const float* Wq = (const float*)d_in[1];
    const float* Wk = (const float*)d_in[2];
    const float* Wv = (const float*)d_in[3];
    const float* Wo = (const float*)d_in[4];
    float* out = (float*)d_out;   // fp32 output

    const size_t QKV_ELEMS = (size_t)BATCH * SEQ * D_MODEL;  // 4194304

    // ws: exactly 4 x 8 MB bf16 buffers = 32 MB
    unsigned short* qb = (unsigned short*)d_ws;
    unsigned short* kb = qb + QKV_ELEMS;
    unsigned short* vb = kb + QKV_ELEMS;
    unsigned short* ab = vb + QKV_ELEMS;

    qkv_mfma_kernel<<<dim3(8, 32, 3), 256, 0, stream>>>(x, Wq, Wk, Wv, qb, kb, vb);
    attn_kernel<<<dim3(32, 32), 256, 0, stream>>>(qb, kb, vb, ab);
    out_mfma_kernel<<<dim3(8, 32), 256, 0, stream>>>(ab, Wo, out);
}

// Round 11
// 394.417 us; speedup vs baseline: 11.2068x; 2.1657x over previous
//
#include <hip/hip_runtime.h>

#define D_MODEL 1024
#define NUM_HEADS 16
#define SEQ 2048
#define BATCH 2

typedef __attribute__((ext_vector_type(8))) short bf16x8;
typedef __attribute__((ext_vector_type(4))) float f32x4;

__device__ __forceinline__ float bf2f(unsigned short u) {
    return __uint_as_float(((unsigned int)u) << 16);
}
__device__ __forceinline__ unsigned short f2bf(float f) {
    unsigned int u = __float_as_uint(f);
    return (unsigned short)((u + 0x7FFFu + ((u >> 16) & 1u)) >> 16);   // RTNE
}
__device__ __forceinline__ ushort4 pack4(float4 v) {
    return make_ushort4(f2bf(v.x), f2bf(v.y), f2bf(v.z), f2bf(v.w));
}

// fp32 -> bf16 bulk convert (one float4 -> ushort4 per thread).
__global__ __launch_bounds__(256) void conv_kernel(
    const float* __restrict__ src, unsigned short* __restrict__ dst, int n4)
{
    int i = blockIdx.x * 256 + threadIdx.x;
    if (i < n4) {
        float4 v = reinterpret_cast<const float4*>(src)[i];
        reinterpret_cast<ushort4*>(dst)[i] = pack4(v);
    }
}

// MFMA NT-GEMM: C[m,n] = sum_i x[m,i] * W[n,i]. x fp32, W bf16 (pre-converted).
// 128x128 tile, BK=32. 1D grid, XCD-swizzled: lin = b + 8*(a + 3*y),
// b = n-strip%8 (-> XCD), a = which (z), y = m-tile. RoPE fused (Q,K).
__global__ __launch_bounds__(256) void qkv_mfma_kernel(
    const float* __restrict__ x,
    const unsigned short* __restrict__ w3,   // [3][1024][1024] bf16
    unsigned short* __restrict__ qb, unsigned short* __restrict__ kb,
    unsigned short* __restrict__ vb)
{
    const int lin = blockIdx.x;
    const int b = lin & 7;
    const int t = lin >> 3;
    const int which = t % 3;
    const int y = t / 3;
    const unsigned short* __restrict__ W = w3 + (size_t)which * 1048576;
    unsigned short* __restrict__ outp = (which == 0) ? qb : ((which == 1) ? kb : vb);
    const int m0 = y * 128;
    const int n0g = b * 128;

    __shared__ __align__(16) unsigned short As[128][40];  // 80 B stride
    __shared__ __align__(16) unsigned short Bs[128][40];

    const int tid = threadIdx.x;
    const int w = tid >> 6;
    const int lane = tid & 63;
    const int quad = lane >> 4;
    const int c15 = lane & 15;
    const int qm = w >> 1, qn = w & 1;

    const int srow = tid >> 1;
    const int scol = (tid & 1) * 16;

    f32x4 acc[4][4];
#pragma unroll
    for (int mi = 0; mi < 4; mi++)
#pragma unroll
        for (int ni = 0; ni < 4; ni++) acc[mi][ni] = (f32x4){0.f, 0.f, 0.f, 0.f};

    for (int kb0 = 0; kb0 < 1024; kb0 += 32) {
        const float* ap = x + (size_t)(m0 + srow) * 1024 + kb0 + scol;
        float4 a0 = *reinterpret_cast<const float4*>(ap + 0);
        float4 a1 = *reinterpret_cast<const float4*>(ap + 4);
        float4 a2 = *reinterpret_cast<const float4*>(ap + 8);
        float4 a3 = *reinterpret_cast<const float4*>(ap + 12);
        const unsigned short* wp = W + (size_t)(n0g + srow) * 1024 + kb0 + scol;
        uint4 b0 = *reinterpret_cast<const uint4*>(wp);
        uint4 b1 = *reinterpret_cast<const uint4*>(wp + 8);

        __syncthreads();
        {
            ushort4* ad = reinterpret_cast<ushort4*>(&As[srow][scol]);
            ad[0] = pack4(a0); ad[1] = pack4(a1); ad[2] = pack4(a2); ad[3] = pack4(a3);
            uint4* bd = reinterpret_cast<uint4*>(&Bs[srow][scol]);
            bd[0] = b0; bd[1] = b1;
        }
        __syncthreads();

        bf16x8 af[4], bfr[4];
#pragma unroll
        for (int mi = 0; mi < 4; mi++)
            af[mi] = *reinterpret_cast<const bf16x8*>(&As[qm * 64 + mi * 16 + c15][quad * 8]);
#pragma unroll
        for (int ni = 0; ni < 4; ni++)
            bfr[ni] = *reinterpret_cast<const bf16x8*>(&Bs[qn * 64 + ni * 16 + c15][quad * 8]);
#pragma unroll
        for (int mi = 0; mi < 4; mi++)
#pragma unroll
            for (int ni = 0; ni < 4; ni++)
                acc[mi][ni] = __builtin_amdgcn_mfma_f32_16x16x32_bf16(af[mi], bfr[ni], acc[mi][ni], 0, 0, 0);
    }

    // Epilogue: RoPE (Q,K) in registers, then wave-private LDS transpose ->
    // coalesced uint4 stores. Wave's n-range = one head: h = b*2 + qn.
    __syncthreads();
    unsigned short* stg = &As[0][0] + w * (16 * 72);   // 16 rows x 72 stride, per wave
    const int hq = b * 2 + qn;

    float invf[4];
#pragma unroll
    for (int ni = 0; ni < 4; ni++)
        invf[ni] = powf(10000.0f, -((float)(((ni * 16 + c15) & 63) >> 1)) / 32.0f);
    const int odd = c15 & 1;

#pragma unroll
    for (int mi = 0; mi < 4; mi++) {
#pragma unroll
        for (int r = 0; r < 4; r++) {
            int m = m0 + qm * 64 + mi * 16 + quad * 4 + r;
            int s = m & (SEQ - 1);
#pragma unroll
            for (int ni = 0; ni < 4; ni++) {
                float val = acc[mi][ni][r];
                float res;
                if (which < 2) {
                    float part = __shfl_xor(val, 1);
                    float sn, cs;
                    sincosf((float)s * invf[ni], &sn, &cs);
                    res = odd ? (part * sn + val * cs) : (val * cs - part * sn);
                } else {
                    res = val;
                }
                stg[(quad * 4 + r) * 72 + ni * 16 + c15] = f2bf(res);
            }
        }
        // read back: 4 lanes per row, 32 B (2 uint4) each -> 128 B contiguous rows
        int row = lane >> 2;
        int ch = lane & 3;
        int m = m0 + qm * 64 + mi * 16 + row;
        int s = m & (SEQ - 1);
        int bb = m >> 11;
        size_t ob = (((size_t)bb * NUM_HEADS + hq) * SEQ + s) * 64 + ch * 16;
        uint4 v0 = *reinterpret_cast<const uint4*>(&stg[row * 72 + ch * 16]);
        uint4 v1 = *reinterpret_cast<const uint4*>(&stg[row * 72 + ch * 16 + 8]);
        *reinterpret_cast<uint4*>(&outp[ob]) = v0;
        *reinterpret_cast<uint4*>(&outp[ob + 8]) = v1;
    }
}

// MFMA flash attention (R9-validated core; epilogue now LDS-staged).
__global__ __launch_bounds__(256) void attn_kernel(
    const unsigned short* __restrict__ qb, const unsigned short* __restrict__ kb,
    const unsigned short* __restrict__ vb, unsigned short* __restrict__ ab)
{
    const int it = blockIdx.x;
    const int bh = blockIdx.y;
    const int b = bh >> 4, h = bh & 15;
    const size_t base = (size_t)bh * SEQ * 64;
    const int tid = threadIdx.x;
    const int w = tid >> 6;
    const int lane = tid & 63;
    const int quad = lane >> 4;
    const int c15 = lane & 15;
    const int i0 = it * 64;

    __shared__ __align__(16) unsigned short Vt[64][72];
    __shared__ __align__(16) unsigned short Pl[64][72];

    const int qrow = i0 + w * 16 + c15;
    bf16x8 qf0 = *reinterpret_cast<const bf16x8*>(&qb[base + (size_t)qrow * 64 + quad * 8]);
    bf16x8 qf1 = *reinterpret_cast<const bf16x8*>(&qb[base + (size_t)qrow * 64 + 32 + quad * 8]);

    float m_st[4], l_st[4];
    f32x4 Oc[4];
#pragma unroll
    for (int r = 0; r < 4; r++) { m_st[r] = -1e30f; l_st[r] = 0.f; }
#pragma unroll
    for (int t = 0; t < 4; t++) Oc[t] = (f32x4){0.f, 0.f, 0.f, 0.f};

    for (int jt = 0; jt <= it; jt++) {
        const int j0 = jt * 64;

        __syncthreads();
        {
            int row = tid & 63;
            int c8 = (tid >> 6) * 8;
#pragma unroll
            for (int u = 0; u < 2; u++) {
                int cc = c8 + u * 32;
                uint4 vv = *reinterpret_cast<const uint4*>(&vb[base + (size_t)(j0 + row) * 64 + cc]);
                const unsigned short* pv = reinterpret_cast<const unsigned short*>(&vv);
#pragma unroll
                for (int e = 0; e < 8; e++) Vt[cc + e][row] = pv[e];
            }
        }
        __syncthreads();

        f32x4 sc[4];
#pragma unroll
        for (int t = 0; t < 4; t++) sc[t] = (f32x4){0.f, 0.f, 0.f, 0.f};
#pragma unroll
        for (int t = 0; t < 4; t++) {
            const unsigned short* kr = &kb[base + (size_t)(j0 + t * 16 + c15) * 64];
            bf16x8 k0 = *reinterpret_cast<const bf16x8*>(kr + quad * 8);
            bf16x8 k1 = *reinterpret_cast<const bf16x8*>(kr + 32 + quad * 8);
            sc[t] = __builtin_amdgcn_mfma_f32_16x16x32_bf16(qf0, k0, sc[t], 0, 0, 0);
            sc[t] = __builtin_amdgcn_mfma_f32_16x16x32_bf16(qf1, k1, sc[t], 0, 0, 0);
        }

#pragma unroll
        for (int t = 0; t < 4; t++)
#pragma unroll
            for (int r = 0; r < 4; r++) sc[t][r] *= 0.125f;
        if (jt == it) {
#pragma unroll
            for (int t = 0; t < 4; t++) {
                int gj = j0 + t * 16 + c15;
#pragma unroll
                for (int r = 0; r < 4; r++) {
                    int gi = i0 + w * 16 + quad * 4 + r;
                    if (gj > gi) sc[t][r] = -1e30f;
                }
            }
        }

        float mnew[4], alpha[4], rsum[4];
#pragma unroll
        for (int r = 0; r < 4; r++) {
            float tm = fmaxf(fmaxf(sc[0][r], sc[1][r]), fmaxf(sc[2][r], sc[3][r]));
            tm = fmaxf(tm, __shfl_xor(tm, 1));
            tm = fmaxf(tm, __shfl_xor(tm, 2));
            tm = fmaxf(tm, __shfl_xor(tm, 4));
            tm = fmaxf(tm, __shfl_xor(tm, 8));
            mnew[r] = fmaxf(m_st[r], tm);
            alpha[r] = __expf(m_st[r] - mnew[r]);
            rsum[r] = 0.f;
        }
#pragma unroll
        for (int t = 0; t < 4; t++) {
#pragma unroll
            for (int r = 0; r < 4; r++) {
                float p = __expf(sc[t][r] - mnew[r]);
                rsum[r] += p;
                Pl[w * 16 + quad * 4 + r][t * 16 + c15] = f2bf(p);
            }
        }
#pragma unroll
        for (int r = 0; r < 4; r++) {
            float s = rsum[r];
            s += __shfl_xor(s, 1);
            s += __shfl_xor(s, 2);
            s += __shfl_xor(s, 4);
            s += __shfl_xor(s, 8);
            l_st[r] = l_st[r] * alpha[r] + s;
            m_st[r] = mnew[r];
#pragma unroll
            for (int t = 0; t < 4; t++) Oc[t][r] *= alpha[r];
        }

        bf16x8 ap0 = *reinterpret_cast<const bf16x8*>(&Pl[w * 16 + c15][quad * 8]);
        bf16x8 ap1 = *reinterpret_cast<const bf16x8*>(&Pl[w * 16 + c15][32 + quad * 8]);
#pragma unroll
        for (int t = 0; t < 4; t++) {
            bf16x8 bv0 = *reinterpret_cast<const bf16x8*>(&Vt[t * 16 + c15][quad * 8]);
            bf16x8 bv1 = *reinterpret_cast<const bf16x8*>(&Vt[t * 16 + c15][32 + quad * 8]);
            Oc[t] = __builtin_amdgcn_mfma_f32_16x16x32_bf16(ap0, bv0, Oc[t], 0, 0, 0);
            Oc[t] = __builtin_amdgcn_mfma_f32_16x16x32_bf16(ap1, bv1, Oc[t], 0, 0, 0);
        }
    }

    // Epilogue: stage O into Pl (wave-private rows), coalesced uint4 stores.
#pragma unroll
    for (int r = 0; r < 4; r++) {
        float inv = 1.0f / l_st[r];
#pragma unroll
        for (int t = 0; t < 4; t++)
            Pl[w * 16 + quad * 4 + r][t * 16 + c15] = f2bf(Oc[t][r] * inv);
    }
    {
        int row = lane >> 2;
        int ch = lane & 3;
        int gi = i0 + w * 16 + row;
        size_t ob = ((size_t)b * SEQ + gi) * 1024 + h * 64 + ch * 16;
        uint4 v0 = *reinterpret_cast<const uint4*>(&Pl[w * 16 + row][ch * 16]);
        uint4 v1 = *reinterpret_cast<const uint4*>(&Pl[w * 16 + row][ch * 16 + 8]);
        *reinterpret_cast<uint4*>(&ab[ob]) = v0;
        *reinterpret_cast<uint4*>(&ab[ob + 8]) = v1;
    }
}

// MFMA NT-GEMM: out[m,n] = sum_i ab[m,i] * Wo[n,i]; both bf16, out fp32.
// 1D grid XCD-swizzled: lin = b + 8*y, b = n-strip (-> XCD).
__global__ __launch_bounds__(256) void out_mfma_kernel(
    const unsigned short* __restrict__ A, const unsigned short* __restrict__ Wob,
    float* __restrict__ out)
{
    const int lin = blockIdx.x;
    const int b = lin & 7;
    const int y = lin >> 3;
    const int m0 = y * 128;
    const int n0g = b * 128;

    __shared__ __align__(16) unsigned short As[128][40];
    __shared__ __align__(16) unsigned short Bs[128][40];

    const int tid = threadIdx.x;
    const int w = tid >> 6;
    const int lane = tid & 63;
    const int quad = lane >> 4;
    const int c15 = lane & 15;
    const int qm = w >> 1, qn = w & 1;

    const int srow = tid >> 1;
    const int scol = (tid & 1) * 16;

    f32x4 acc[4][4];
#pragma unroll
    for (int mi = 0; mi < 4; mi++)
#pragma unroll
        for (int ni = 0; ni < 4; ni++) acc[mi][ni] = (f32x4){0.f, 0.f, 0.f, 0.f};

    for (int kb0 = 0; kb0 < 1024; kb0 += 32) {
        const unsigned short* ap = A + (size_t)(m0 + srow) * 1024 + kb0 + scol;
        uint4 a0 = *reinterpret_cast<const uint4*>(ap);
        uint4 a1 = *reinterpret_cast<const uint4*>(ap + 8);
        const unsigned short* wp = Wob + (size_t)(n0g + srow) * 1024 + kb0 + scol;
        uint4 b0 = *reinterpret_cast<const uint4*>(wp);
        uint4 b1 = *reinterpret_cast<const uint4*>(wp + 8);

        __syncthreads();
        {
            uint4* ad = reinterpret_cast<uint4*>(&As[srow][scol]);
            ad[0] = a0; ad[1] = a1;
            uint4* bd = reinterpret_cast<uint4*>(&Bs[srow][scol]);
            bd[0] = b0; bd[1] = b1;
        }
        __syncthreads();

        bf16x8 af[4], bfr[4];
#pragma unroll
        for (int mi = 0; mi < 4; mi++)
            af[mi] = *reinterpret_cast<const bf16x8*>(&As[qm * 64 + mi * 16 + c15][quad * 8]);
#pragma unroll
        for (int ni = 0; ni < 4; ni++)
            bfr[ni] = *reinterpret_cast<const bf16x8*>(&Bs[qn * 64 + ni * 16 + c15][quad * 8]);
#pragma unroll
        for (int mi = 0; mi < 4; mi++)
#pragma unroll
            for (int ni = 0; ni < 4; ni++)
                acc[mi][ni] = __builtin_amdgcn_mfma_f32_16x16x32_bf16(af[mi], bfr[ni], acc[mi][ni], 0, 0, 0);
    }

    // fp32 stores: 16 lanes x 4 B = 64 B contiguous per quad-row — OK direct.
#pragma unroll
    for (int mi = 0; mi < 4; mi++) {
#pragma unroll
        for (int r = 0; r < 4; r++) {
            int m = m0 + qm * 64 + mi * 16 + quad * 4 + r;
#pragma unroll
            for (int ni = 0; ni < 4; ni++) {
                int n = n0g + qn * 64 + ni * 16 + c15;
                out[(size_t)m * 1024 + n] = acc[mi][ni][r];
            }
        }
    }
}

extern "C" void kernel_launch(void* const* d_in, const int* in_sizes, int n_in,
                              void* d_out, int out_size, void* d_ws, size_t ws_size,
                              hipStream_t stream)
{
    const float* x  = (const float*)d_in[0];
    const float* Wq = (const float*)d_in[1];
    const float* Wk = (const float*)d_in[2];
    const float* Wv = (const float*)d_in[3];
    const float* Wo = (const float*)d_in[4];
    float* out = (float*)d_out;

    const size_t QKV_ELEMS = (size_t)BATCH * SEQ * D_MODEL;  // 4194304

    unsigned short* qb = (unsigned short*)d_ws;
    unsigned short* kb = qb + QKV_ELEMS;
    unsigned short* vb = kb + QKV_ELEMS;
    unsigned short* ab = vb + QKV_ELEMS;
    // dead-region reuse: W3 bf16 lives in ab during qkv; Wo bf16 in qb during out.
    unsigned short* w3bf = ab;     // 3 * 1048576 bf16 = 6.3 MB <= 8.4 MB
    unsigned short* wobf = qb;     // 2.1 MB

    conv_kernel<<<dim3(3072), 256, 0, stream>>>(Wq, w3bf, 262144);
    conv_kernel<<<dim3(3072), 256, 0, stream>>>(Wk, w3bf + 1048576, 262144);
    conv_kernel<<<dim3(3072), 256, 0, stream>>>(Wv, w3bf + 2097152, 262144);
    qkv_mfma_kernel<<<dim3(768), 256, 0, stream>>>(x, w3bf, qb, kb, vb);
    attn_kernel<<<dim3(32, 32), 256, 0, stream>>>(qb, kb, vb, ab);
    conv_kernel<<<dim3(1024), 256, 0, stream>>>(Wo, wobf, 262144);
    out_mfma_kernel<<<dim3(256), 256, 0, stream>>>(ab, wobf, out);
}